// Round 14
// baseline (449.798 us; speedup 1.0000x reference)
//
#include <hip/hip_runtime.h>
#include <math.h>

typedef float f4 __attribute__((ext_vector_type(4)));
typedef float f32x4 __attribute__((ext_vector_type(4)));
typedef float f32x2 __attribute__((ext_vector_type(2)));
typedef short bf16x8 __attribute__((ext_vector_type(8)));
typedef unsigned int u32x2 __attribute__((ext_vector_type(2)));
typedef int i32x4 __attribute__((ext_vector_type(4)));
typedef unsigned short u16x4 __attribute__((ext_vector_type(4)));

// ---------------- device helpers ----------------
__device__ __forceinline__ float lrelu(float x) { return x >= 0.f ? x : 0.2f * x; }
__device__ __forceinline__ float eluf(float x)  { return x > 0.f ? x : __expf(x) - 1.f; }

__device__ __forceinline__ float bf2f(unsigned short u) {
    union { unsigned int i; float f; } c; c.i = ((unsigned int)u) << 16; return c.f;
}
__device__ __forceinline__ unsigned short f2bf(float f) {
    union { float f; unsigned int i; } c; c.f = f;
    unsigned int r = c.i + 0x7fffu + ((c.i >> 16) & 1u);   // RNE
    return (unsigned short)(r >> 16);
}
__device__ __forceinline__ unsigned char f2f8(float f) {
    return (unsigned char)(__builtin_amdgcn_cvt_pk_fp8_f32(f, f, 0u, false) & 0xffu);
}

// ---------------- fused: deg+rank, weight packs, L1 combined score weights ----------------
__global__ void k_deg_pack(const int* __restrict__ edst, int* __restrict__ deg,
                           unsigned short* __restrict__ rank, int E, int DB,
                           const float* __restrict__ w2, unsigned short* __restrict__ w2p,
                           const float* __restrict__ w3, unsigned short* __restrict__ w3p,
                           const float* __restrict__ w1, const float* __restrict__ as1,
                           const float* __restrict__ ad1, float* __restrict__ cw) {
    int b = blockIdx.x;
    int tid = threadIdx.x;
    if (b < DB) {
        int base = (b * 256 + tid) * 4;
        if (base + 3 < E) {
            i32x4 d = *reinterpret_cast<const i32x4*>(&edst[base]);
            u16x4 r;
            r.x = (unsigned short)atomicAdd(&deg[d.x], 1);
            r.y = (unsigned short)atomicAdd(&deg[d.y], 1);
            r.z = (unsigned short)atomicAdd(&deg[d.z], 1);
            r.w = (unsigned short)atomicAdd(&deg[d.w], 1);
            *reinterpret_cast<u16x4*>(&rank[base]) = r;
        } else {
            for (int e = base; e < E; ++e)
                rank[e] = (unsigned short)atomicAdd(&deg[edst[e]], 1);
        }
    } else if (b < DB + 256) {
        int i = (b - DB) * 256 + tid;          // w2: 256x256
        int k = i >> 8, c = i & 255;
        w2p[((size_t)(k >> 3) * 256 + c) * 8 + (k & 7)] = f2bf(w2[i]);
    } else if (b < DB + 256 + 32) {
        int i = (b - DB - 256) * 256 + tid;    // w3: 256x32
        int k = i >> 5, c = i & 31;
        w3p[((size_t)(k >> 3) * 32 + c) * 8 + (k & 7)] = f2bf(w3[i]);
    } else {
        if (tid < 168) {                       // cw: 21x8 combined score weights
            int k = tid >> 3, j = tid & 7;
            int h = j >> 1;
            const float* av = (j & 1) ? ad1 : as1;
            float s = 0.f;
            for (int c = 0; c < 64; ++c)
                s = fmaf(w1[k * 256 + h * 64 + c], av[h * 64 + c], s);
            cw[k * 8 + j] = s;
        }
    }
}

// ---- multi-block exclusive scan over deg[N] -> offs[N+1] ----
__global__ __launch_bounds__(1024) void k_scan1(const int* __restrict__ deg,
                                                int* __restrict__ bsum, int N) {
    int t = threadIdx.x;
    int i = blockIdx.x * 1024 + t;
    int v = (i < N) ? deg[i] : 0;
#pragma unroll
    for (int m = 32; m; m >>= 1) v += __shfl_xor(v, m);
    __shared__ int ws[16];
    if ((t & 63) == 0) ws[t >> 6] = v;
    __syncthreads();
    if (t < 16) {
        int s = ws[t];
#pragma unroll
        for (int m = 8; m; m >>= 1) s += __shfl_xor(s, m);
        if (t == 0) bsum[blockIdx.x] = s;
    }
}

__global__ void k_scan2(int* __restrict__ bsum, int B) {
    __shared__ int sm[256];
    int t = threadIdx.x;
    int v = (t < B) ? bsum[t] : 0;
    sm[t] = v;
    __syncthreads();
    for (int d = 1; d < 256; d <<= 1) {
        int x = (t >= d) ? sm[t - d] : 0;
        __syncthreads();
        sm[t] += x;
        __syncthreads();
    }
    if (t < B) bsum[t] = sm[t] - v;
}

__global__ __launch_bounds__(1024) void k_scan3(const int* __restrict__ deg,
                                                const int* __restrict__ bsum,
                                                int* __restrict__ offs, int N) {
    __shared__ int sm[1024];
    int t = threadIdx.x;
    int i = blockIdx.x * 1024 + t;
    int v = (i < N) ? deg[i] : 0;
    sm[t] = v;
    __syncthreads();
    for (int d = 1; d < 1024; d <<= 1) {
        int x = (t >= d) ? sm[t - d] : 0;
        __syncthreads();
        sm[t] += x;
        __syncthreads();
    }
    int pref = bsum[blockIdx.x] + sm[t] - v;
    if (i < N) offs[i] = pref;
    if (i == N - 1) offs[N] = pref + v;
}

// ---------------- atomic-free scatter: csr[offs[dst]+rank] = src ----------------
__global__ void k_scatter(const int* __restrict__ esrc, const int* __restrict__ edst,
                          const unsigned short* __restrict__ rank,
                          const int* __restrict__ offs, int* __restrict__ csr, int E) {
    int base = (blockIdx.x * 256 + threadIdx.x) * 4;
    if (base + 3 < E) {
        i32x4 s = *reinterpret_cast<const i32x4*>(&esrc[base]);
        i32x4 d = *reinterpret_cast<const i32x4*>(&edst[base]);
        u16x4 r = *reinterpret_cast<const u16x4*>(&rank[base]);
        csr[offs[d.x] + r.x] = s.x;
        csr[offs[d.y] + r.y] = s.y;
        csr[offs[d.z] + r.z] = s.z;
        csr[offs[d.w] + r.w] = s.w;
    } else {
        for (int e = base; e < E; ++e) csr[offs[edst[e]] + rank[e]] = esrc[e];
    }
}

// ---------------- L1 GEMM (VALU, K=21) -> h fp8; scores via x @ cw ----------------
__global__ void k_gemm1(const float* __restrict__ x, const float* __restrict__ w,
                        const float* __restrict__ cw,
                        unsigned char* __restrict__ h8, float* __restrict__ asb,
                        float* __restrict__ adb, int N) {
    int tid = threadIdx.x;
    int row0 = blockIdx.x * 8;
    __shared__ float xs[8][21];
    int nrows = min(8, N - row0);
    for (int i = tid; i < nrows * 21; i += 256) xs[i / 21][i % 21] = x[row0 * 21 + i];
    __syncthreads();
    float wreg[21];
#pragma unroll
    for (int k = 0; k < 21; ++k) wreg[k] = w[k * 256 + tid];
    for (int r = 0; r < nrows; ++r) {
        float acc = 0.f;
#pragma unroll
        for (int k = 0; k < 21; ++k) acc = fmaf(xs[r][k], wreg[k], acc);
        h8[(size_t)(row0 + r) * 256 + tid] = f2f8(acc);
    }
    if (tid < 64) {
        int r = tid >> 3, j = tid & 7;
        if (r < nrows) {
            float s = 0.f;
#pragma unroll
            for (int k = 0; k < 21; ++k) s = fmaf(xs[r][k], cw[k * 8 + j], s);
            int row = row0 + r;
            if (j & 1) adb[row * 4 + (j >> 1)] = s;
            else       asb[row * 4 + (j >> 1)] = s;
        }
    }
}

// ---------------- L2 GEMM via MFMA (col-split waves) ----------------
__global__ __launch_bounds__(256) void k_gemm2_mfma(
        const unsigned short* __restrict__ in, const unsigned short* __restrict__ w2p,
        const float* __restrict__ as2f, const float* __restrict__ ad2f,
        unsigned char* __restrict__ h8, float* __restrict__ asb,
        float* __restrict__ adb, int N) {
    int tid = threadIdx.x;
    int wave = tid >> 6, lane = tid & 63;
    int g = lane >> 4, q = lane & 15;
    int row0 = blockIdx.x * 64;

    f32x4 acc[4][4];   // [row-group][cc]
#pragma unroll
    for (int rg = 0; rg < 4; ++rg)
#pragma unroll
        for (int cc = 0; cc < 4; ++cc) acc[rg][cc] = (f32x4)0.f;

    const unsigned short* aptr = in + (size_t)(row0 + q) * 256 + g * 8;
    const unsigned short* bptr = w2p + ((size_t)g * 256 + q) * 8 + wave * 512;

#pragma unroll
    for (int kt = 0; kt < 8; ++kt) {
        bf16x8 a[4];
#pragma unroll
        for (int rg = 0; rg < 4; ++rg)
            a[rg] = *reinterpret_cast<const bf16x8*>(aptr + (size_t)rg * 16 * 256 + kt * 32);
#pragma unroll
        for (int cc = 0; cc < 4; ++cc) {
            bf16x8 b = *reinterpret_cast<const bf16x8*>(bptr + (size_t)kt * 8192 + cc * 128);
#pragma unroll
            for (int rg = 0; rg < 4; ++rg)
                acc[rg][cc] = __builtin_amdgcn_mfma_f32_16x16x32_bf16(a[rg], b, acc[rg][cc], 0, 0, 0);
        }
    }

#pragma unroll
    for (int rg = 0; rg < 4; ++rg) {
#pragma unroll
        for (int cc = 0; cc < 4; ++cc) {
            int col = (wave * 4 + cc) * 16 + q;
#pragma unroll
            for (int r = 0; r < 4; ++r) {
                int row = row0 + rg * 16 + 4 * g + r;
                if (row < N) h8[(size_t)row * 256 + col] = f2f8(acc[rg][cc][r]);
            }
        }
    }

#pragma unroll
    for (int rg = 0; rg < 4; ++rg) {
        float s1[4] = {0.f, 0.f, 0.f, 0.f}, s2[4] = {0.f, 0.f, 0.f, 0.f};
#pragma unroll
        for (int cc = 0; cc < 4; ++cc) {
            int col = (wave * 4 + cc) * 16 + q;
            float ws_ = as2f[col], wd_ = ad2f[col];
#pragma unroll
            for (int r = 0; r < 4; ++r) {
                s1[r] = fmaf(acc[rg][cc][r], ws_, s1[r]);
                s2[r] = fmaf(acc[rg][cc][r], wd_, s2[r]);
            }
        }
#pragma unroll
        for (int m = 1; m < 16; m <<= 1) {
#pragma unroll
            for (int r = 0; r < 4; ++r) {
                s1[r] += __shfl_xor(s1[r], m);
                s2[r] += __shfl_xor(s2[r], m);
            }
        }
        if (q == 0) {
#pragma unroll
            for (int r = 0; r < 4; ++r) {
                int row = row0 + rg * 16 + 4 * g + r;
                if (row < N) { asb[row * 4 + wave] = s1[r]; adb[row * 4 + wave] = s2[r]; }
            }
        }
    }
}

// ---------------- L3 GEMM via MFMA -> h3 fp32 + scores ----------------
__global__ __launch_bounds__(256) void k_gemm3_mfma(
        const unsigned short* __restrict__ in, const unsigned short* __restrict__ w3p,
        const float* __restrict__ as3f, const float* __restrict__ ad3f,
        float* __restrict__ h3, float* __restrict__ asb, float* __restrict__ adb, int N) {
    int tid = threadIdx.x;
    int wave = tid >> 6, lane = tid & 63;
    int g = lane >> 4, q = lane & 15;
    int row0 = blockIdx.x * 64 + wave * 16;

    f32x4 acc[2];
    acc[0] = (f32x4)0.f; acc[1] = (f32x4)0.f;

    const unsigned short* aptr = in + (size_t)(row0 + q) * 256 + g * 8;
    const unsigned short* bptr = w3p + ((size_t)g * 32 + q) * 8;

#pragma unroll
    for (int kt = 0; kt < 8; ++kt) {
        bf16x8 a = *reinterpret_cast<const bf16x8*>(aptr + kt * 32);
#pragma unroll
        for (int ct = 0; ct < 2; ++ct) {
            bf16x8 b = *reinterpret_cast<const bf16x8*>(bptr + (size_t)kt * 1024 + ct * 128);
            acc[ct] = __builtin_amdgcn_mfma_f32_16x16x32_bf16(a, b, acc[ct], 0, 0, 0);
        }
    }

    float s1[4] = {0.f, 0.f, 0.f, 0.f}, s2[4] = {0.f, 0.f, 0.f, 0.f};
#pragma unroll
    for (int ct = 0; ct < 2; ++ct) {
        int col = ct * 16 + q;
        float ws_ = as3f[col], wd_ = ad3f[col];
#pragma unroll
        for (int r = 0; r < 4; ++r) {
            int row = row0 + 4 * g + r;
            if (row < N) h3[(size_t)row * 32 + col] = acc[ct][r];
            s1[r] = fmaf(acc[ct][r], ws_, s1[r]);
            s2[r] = fmaf(acc[ct][r], wd_, s2[r]);
        }
    }
#pragma unroll
    for (int m = 1; m < 16; m <<= 1) {
#pragma unroll
        for (int r = 0; r < 4; ++r) {
            s1[r] += __shfl_xor(s1[r], m);
            s2[r] += __shfl_xor(s2[r], m);
        }
    }
    if (q == 0) {
#pragma unroll
        for (int r = 0; r < 4; ++r) {
            int row = row0 + 4 * g + r;
            if (row < N) { asb[row] = s1[r]; adb[row] = s2[r]; }
        }
    }
}

// ---------------- gather (attention aggregate), F=256 fp8 -> bf16, 4 heads ----------------
// deferred den (per-lane partials, one group-reduce at end), row-offset broadcast,
// packed f32x2 accumulate.
__global__ void k_gather256(const unsigned int* __restrict__ h8,
                            const float* __restrict__ asb, const float* __restrict__ adb,
                            const int* __restrict__ offs, const int* __restrict__ csr,
                            const float* __restrict__ bias, unsigned short* __restrict__ out,
                            int N) {
    int tid = threadIdx.x;
    int lane = tid & 63;
    int v = blockIdx.x * 4 + (tid >> 6);
    if (v >= N) return;
    int head = lane >> 4;
    int j16 = lane & 15;
    int gbase = lane & 48;          // head-group base lane
    float ad = adb[v * 4 + head];
    float w0 = __expf(lrelu(asb[v * 4 + head] + ad));
    f32x2 a01, a23;
    {
        unsigned int hv = h8[(size_t)v * 64 + lane];
        f32x2 lo = __builtin_amdgcn_cvt_pk_f32_fp8(hv, false);
        f32x2 hi = __builtin_amdgcn_cvt_pk_f32_fp8(hv, true);
        a01 = (f32x2)w0 * lo; a23 = (f32x2)w0 * hi;
    }
    float denp = 0.f;               // per-lane weight partial (self-loop added after reduce)
    const unsigned int* hrow = h8 + lane;
    int beg = offs[v], end = offs[v + 1];
    for (int c = beg; c < end; c += 16) {
        int idx = c + j16;
        unsigned int uo = 0;
        float w = 0.f;
        if (idx < end) {
            int u = csr[idx];
            w = __expf(lrelu(asb[u * 4 + head] + ad));
            uo = (unsigned int)u * 64u;  // row dword-offset
        }
        denp += w;
#pragma unroll
        for (int j = 0; j < 16; ++j) {
            float wj         = __shfl(w, gbase | j);
            unsigned int uoj = __shfl(uo, gbase | j);
            unsigned int hv = hrow[(size_t)uoj];
            f32x2 lo = __builtin_amdgcn_cvt_pk_f32_fp8(hv, false);
            f32x2 hi = __builtin_amdgcn_cvt_pk_f32_fp8(hv, true);
            a01 += (f32x2)wj * lo;
            a23 += (f32x2)wj * hi;
        }
    }
#pragma unroll
    for (int m = 1; m < 16; m <<= 1) denp += __shfl_xor(denp, m);
    float inv = 1.f / (denp + w0 + 1e-16f);
    int f0 = 4 * lane;
    unsigned int w01 = (unsigned int)f2bf(eluf(a01.x * inv + bias[f0 + 0]))
                     | ((unsigned int)f2bf(eluf(a01.y * inv + bias[f0 + 1])) << 16);
    unsigned int w23 = (unsigned int)f2bf(eluf(a23.x * inv + bias[f0 + 2]))
                     | ((unsigned int)f2bf(eluf(a23.y * inv + bias[f0 + 3])) << 16);
    u32x2 o; o.x = w01; o.y = w23;
    __builtin_nontemporal_store(o, reinterpret_cast<u32x2*>(&out[(size_t)v * 256 + f0]));
}

// ---------------- gather, F=32 fp32, 1 head — chunked ILP, deferred den ----------------
__global__ void k_gather32(const float* __restrict__ h, const float* __restrict__ asb,
                           const float* __restrict__ adb, const int* __restrict__ offs,
                           const int* __restrict__ csr, const float* __restrict__ bias,
                           float* __restrict__ out, int N) {
    int tid = threadIdx.x;
    int v = blockIdx.x * 8 + (tid >> 5);
    int c = tid & 31;
    int gbase = tid & 32;           // 32-lane group base within the wave
    if (v >= N) return;
    float ad = adb[v];
    float w0 = __expf(lrelu(asb[v] + ad));
    float acc = w0 * h[(size_t)v * 32 + c];
    float denp = 0.f;
    const float* hrow = h + c;
    int beg = offs[v], end = offs[v + 1];
    for (int e0 = beg; e0 < end; e0 += 32) {
        int idx = e0 + c;
        unsigned int uo = 0;
        float w = 0.f;
        if (idx < end) {
            int u = csr[idx];
            w = __expf(lrelu(asb[u] + ad));
            uo = (unsigned int)u * 32u;
        }
        denp += w;
#pragma unroll
        for (int j = 0; j < 32; ++j) {
            float wj         = __shfl(w, gbase | j);
            unsigned int uoj = __shfl(uo, gbase | j);
            acc = fmaf(wj, hrow[(size_t)uoj], acc);
        }
    }
#pragma unroll
    for (int m = 1; m < 32; m <<= 1) denp += __shfl_xor(denp, m);
    float o = eluf(acc / (denp + w0 + 1e-16f) + bias[c]);
    __builtin_nontemporal_store(o, &out[(size_t)v * 32 + c]);
}

// ---------------- fused mean-pool + MLP head ----------------
__global__ __launch_bounds__(256) void k_pool_head(
        const float* __restrict__ h, const int* __restrict__ batch, int N,
        const float* __restrict__ fw1, const float* __restrict__ fb1,
        const float* __restrict__ fw2, const float* __restrict__ fb2,
        const float* __restrict__ fw3, const float* __restrict__ fb3,
        float* __restrict__ out, int G) {
    int g = blockIdx.x;
    int tid = threadIdx.x;
    __shared__ int bounds[2];
    __shared__ float red[8][32];
    __shared__ float pooled[32];
    __shared__ float t1[64];
    __shared__ float t2[32];

    if (tid < 2) {
        int target = g + tid;
        int lo = 0, hi = N;
        while (lo < hi) {
            int mid = (lo + hi) >> 1;
            if (batch[mid] < target) lo = mid + 1; else hi = mid;
        }
        bounds[tid] = lo;
    }
    __syncthreads();
    int beg = bounds[0], end = bounds[1];

    int f = tid & 31, r = tid >> 5;
    float s = 0.f;
    for (int i = beg + r; i < end; i += 8) s += h[(size_t)i * 32 + f];
    red[r][f] = s;
    __syncthreads();

    if (tid < 32) {
        float t = 0.f;
#pragma unroll
        for (int k = 0; k < 8; ++k) t += red[k][tid];
        float invc = 1.f / fmaxf((float)(end - beg), 1.f);
        pooled[tid] = t * invc;
    }
    __syncthreads();

    if (tid < 64) {
        float a = fb1[tid];
#pragma unroll
        for (int k = 0; k < 32; ++k) a = fmaf(pooled[k], fw1[k * 64 + tid], a);
        t1[tid] = fmaxf(a, 0.f);
    }
    __syncthreads();
    if (tid < 32) {
        float a = fb2[tid];
#pragma unroll
        for (int k = 0; k < 64; ++k) a = fmaf(t1[k], fw2[k * 32 + tid], a);
        t2[tid] = fmaxf(a, 0.f);
    }
    __syncthreads();
    if (tid == 0) {
        float o = fb3[0];
#pragma unroll
        for (int k = 0; k < 32; ++k) o = fmaf(t2[k], fw3[k], o);
        out[g] = 1.f / (1.f + __expf(-o));
    }
}

// ---------------- host ----------------
extern "C" void kernel_launch(void* const* d_in, const int* in_sizes, int n_in,
                              void* d_out, int out_size, void* d_ws, size_t ws_size,
                              hipStream_t stream) {
    const float* x    = (const float*)d_in[0];
    const int*   ei   = (const int*)d_in[1];
    const int*   batch= (const int*)d_in[2];
    const float* w1   = (const float*)d_in[3];
    const float* as1  = (const float*)d_in[4];
    const float* ad1  = (const float*)d_in[5];
    const float* b1   = (const float*)d_in[6];
    const float* w2   = (const float*)d_in[7];
    const float* as2  = (const float*)d_in[8];
    const float* ad2  = (const float*)d_in[9];
    const float* b2   = (const float*)d_in[10];
    const float* w3   = (const float*)d_in[11];
    const float* as3  = (const float*)d_in[12];
    const float* ad3  = (const float*)d_in[13];
    const float* b3   = (const float*)d_in[14];
    const float* fw1  = (const float*)d_in[15];
    const float* fb1  = (const float*)d_in[16];
    const float* fw2  = (const float*)d_in[17];
    const float* fb2  = (const float*)d_in[18];
    const float* fw3  = (const float*)d_in[19];
    const float* fb3  = (const float*)d_in[20];
    float* outp = (float*)d_out;

    const int N = in_sizes[0] / 21;
    const int E = in_sizes[1] / 2;
    const int G = out_size;

    // ---- workspace carve ----
    char* p = (char*)d_ws;
    auto alloc = [&](size_t bytes) -> void* {
        void* r = (void*)p;
        p += (bytes + 255) & ~(size_t)255;
        return r;
    };
    int*   deg  = (int*)alloc((size_t)N * 4);
    int*   offs = (int*)alloc((size_t)(N + 1) * 4);
    int*   csr  = (int*)alloc((size_t)E * 4);
    unsigned short* rank = (unsigned short*)alloc((size_t)E * 2);
    int*   bsum = (int*)alloc((size_t)256 * 4);
    unsigned char*  h8  = (unsigned char*)alloc((size_t)N * 256);       // fp8 gather operand
    unsigned short* hbf = (unsigned short*)alloc((size_t)N * 256 * 2);  // bf16 gather output
    float* h3   = (float*)alloc((size_t)N * 32 * 4);
    float* hP   = (float*)alloc((size_t)N * 32 * 4);
    float* asb  = (float*)alloc((size_t)N * 4 * 4);
    float* adb  = (float*)alloc((size_t)N * 4 * 4);
    unsigned short* w2p = (unsigned short*)alloc((size_t)256 * 256 * 2);
    unsigned short* w3p = (unsigned short*)alloc((size_t)256 * 32 * 2);
    float* cw   = (float*)alloc((size_t)21 * 8 * 4);                    // L1 combined score weights

    const int* esrc = ei;
    const int* edst = ei + E;

    (void)hipMemsetAsync(deg, 0, (size_t)N * 4, stream);

    const int sb = (N + 1023) / 1024;          // scan blocks (<= 256)
    const int DB = (E + 1023) / 1024;          // deg blocks (4 edges/thread)
    const int SB = (E + 1023) / 1024;          // scatter blocks (4 edges/thread)

    // ---- CSR build: deg+rank+packs+cw, scan, atomic-free scatter ----
    k_deg_pack<<<DB + 256 + 32 + 1, 256, 0, stream>>>(edst, deg, rank, E, DB,
                                                      w2, w2p, w3, w3p, w1, as1, ad1, cw);
    k_scan1<<<sb, 1024, 0, stream>>>(deg, bsum, N);
    k_scan2<<<1, 256, 0, stream>>>(bsum, sb);
    k_scan3<<<sb, 1024, 0, stream>>>(deg, bsum, offs, N);
    k_scatter<<<SB, 256, 0, stream>>>(esrc, edst, rank, offs, csr, E);

    const int gblk = (N + 63) / 64;

    // ---- layer 1 ----
    k_gemm1<<<(N + 7) / 8, 256, 0, stream>>>(x, w1, cw, h8, asb, adb, N);
    k_gather256<<<(N + 3) / 4, 256, 0, stream>>>((const unsigned int*)h8, asb, adb, offs, csr, b1, hbf, N);

    // ---- layer 2 ----
    k_gemm2_mfma<<<gblk, 256, 0, stream>>>(hbf, w2p, as2, ad2, h8, asb, adb, N);
    k_gather256<<<(N + 3) / 4, 256, 0, stream>>>((const unsigned int*)h8, asb, adb, offs, csr, b2, hbf, N);

    // ---- layer 3 ----
    k_gemm3_mfma<<<gblk, 256, 0, stream>>>(hbf, w3p, as3, ad3, h3, asb, adb, N);
    k_gather32<<<(N + 7) / 8, 256, 0, stream>>>(h3, asb, adb, offs, csr, b3, hP, N);

    // ---- fused pool + head ----
    k_pool_head<<<G, 256, 0, stream>>>(hP, batch, N, fw1, fb1, fw2, fb2, fw3, fb3, outp, G);
}

// Round 15
// 438.329 us; speedup vs baseline: 1.0262x; 1.0262x over previous
//
#include <hip/hip_runtime.h>
#include <math.h>

typedef float f4 __attribute__((ext_vector_type(4)));
typedef float f32x4 __attribute__((ext_vector_type(4)));
typedef float f32x2 __attribute__((ext_vector_type(2)));
typedef short bf16x8 __attribute__((ext_vector_type(8)));
typedef unsigned int u32x2 __attribute__((ext_vector_type(2)));
typedef int i32x4 __attribute__((ext_vector_type(4)));
typedef unsigned short u16x4 __attribute__((ext_vector_type(4)));

// ---------------- device helpers ----------------
__device__ __forceinline__ float lrelu(float x) { return x >= 0.f ? x : 0.2f * x; }
__device__ __forceinline__ float eluf(float x)  { return x > 0.f ? x : __expf(x) - 1.f; }

__device__ __forceinline__ float bf2f(unsigned short u) {
    union { unsigned int i; float f; } c; c.i = ((unsigned int)u) << 16; return c.f;
}
__device__ __forceinline__ unsigned short f2bf(float f) {
    union { float f; unsigned int i; } c; c.f = f;
    unsigned int r = c.i + 0x7fffu + ((c.i >> 16) & 1u);   // RNE
    return (unsigned short)(r >> 16);
}
__device__ __forceinline__ unsigned char f2f8(float f) {
    return (unsigned char)(__builtin_amdgcn_cvt_pk_fp8_f32(f, f, 0u, false) & 0xffu);
}

// ---------------- fused: deg+rank, weight packs, L1 combined score weights ----------------
__global__ void k_deg_pack(const int* __restrict__ edst, int* __restrict__ deg,
                           unsigned short* __restrict__ rank, int E, int DB,
                           const float* __restrict__ w2, unsigned short* __restrict__ w2p,
                           const float* __restrict__ w3, unsigned short* __restrict__ w3p,
                           const float* __restrict__ w1, const float* __restrict__ as1,
                           const float* __restrict__ ad1, float* __restrict__ cw) {
    int b = blockIdx.x;
    int tid = threadIdx.x;
    if (b < DB) {
        int base = (b * 256 + tid) * 4;
        if (base + 3 < E) {
            i32x4 d = *reinterpret_cast<const i32x4*>(&edst[base]);
            u16x4 r;
            r.x = (unsigned short)atomicAdd(&deg[d.x], 1);
            r.y = (unsigned short)atomicAdd(&deg[d.y], 1);
            r.z = (unsigned short)atomicAdd(&deg[d.z], 1);
            r.w = (unsigned short)atomicAdd(&deg[d.w], 1);
            *reinterpret_cast<u16x4*>(&rank[base]) = r;
        } else {
            for (int e = base; e < E; ++e)
                rank[e] = (unsigned short)atomicAdd(&deg[edst[e]], 1);
        }
    } else if (b < DB + 256) {
        int i = (b - DB) * 256 + tid;          // w2: 256x256
        int k = i >> 8, c = i & 255;
        w2p[((size_t)(k >> 3) * 256 + c) * 8 + (k & 7)] = f2bf(w2[i]);
    } else if (b < DB + 256 + 32) {
        int i = (b - DB - 256) * 256 + tid;    // w3: 256x32
        int k = i >> 5, c = i & 31;
        w3p[((size_t)(k >> 3) * 32 + c) * 8 + (k & 7)] = f2bf(w3[i]);
    } else {
        if (tid < 168) {                       // cw: 21x8 combined score weights
            int k = tid >> 3, j = tid & 7;
            int h = j >> 1;
            const float* av = (j & 1) ? ad1 : as1;
            float s = 0.f;
            for (int c = 0; c < 64; ++c)
                s = fmaf(w1[k * 256 + h * 64 + c], av[h * 64 + c], s);
            cw[k * 8 + j] = s;
        }
    }
}

// ---- multi-block exclusive scan over deg[N] -> offs[N+1] ----
__global__ __launch_bounds__(1024) void k_scan1(const int* __restrict__ deg,
                                                int* __restrict__ bsum, int N) {
    int t = threadIdx.x;
    int i = blockIdx.x * 1024 + t;
    int v = (i < N) ? deg[i] : 0;
#pragma unroll
    for (int m = 32; m; m >>= 1) v += __shfl_xor(v, m);
    __shared__ int ws[16];
    if ((t & 63) == 0) ws[t >> 6] = v;
    __syncthreads();
    if (t < 16) {
        int s = ws[t];
#pragma unroll
        for (int m = 8; m; m >>= 1) s += __shfl_xor(s, m);
        if (t == 0) bsum[blockIdx.x] = s;
    }
}

__global__ void k_scan2(int* __restrict__ bsum, int B) {
    __shared__ int sm[256];
    int t = threadIdx.x;
    int v = (t < B) ? bsum[t] : 0;
    sm[t] = v;
    __syncthreads();
    for (int d = 1; d < 256; d <<= 1) {
        int x = (t >= d) ? sm[t - d] : 0;
        __syncthreads();
        sm[t] += x;
        __syncthreads();
    }
    if (t < B) bsum[t] = sm[t] - v;
}

__global__ __launch_bounds__(1024) void k_scan3(const int* __restrict__ deg,
                                                const int* __restrict__ bsum,
                                                int* __restrict__ offs, int N) {
    __shared__ int sm[1024];
    int t = threadIdx.x;
    int i = blockIdx.x * 1024 + t;
    int v = (i < N) ? deg[i] : 0;
    sm[t] = v;
    __syncthreads();
    for (int d = 1; d < 1024; d <<= 1) {
        int x = (t >= d) ? sm[t - d] : 0;
        __syncthreads();
        sm[t] += x;
        __syncthreads();
    }
    int pref = bsum[blockIdx.x] + sm[t] - v;
    if (i < N) offs[i] = pref;
    if (i == N - 1) offs[N] = pref + v;
}

// ---------------- atomic-free scatter: csr[offs[dst]+rank] = src ----------------
__global__ void k_scatter(const int* __restrict__ esrc, const int* __restrict__ edst,
                          const unsigned short* __restrict__ rank,
                          const int* __restrict__ offs, int* __restrict__ csr, int E) {
    int base = (blockIdx.x * 256 + threadIdx.x) * 4;
    if (base + 3 < E) {
        i32x4 s = *reinterpret_cast<const i32x4*>(&esrc[base]);
        i32x4 d = *reinterpret_cast<const i32x4*>(&edst[base]);
        u16x4 r = *reinterpret_cast<const u16x4*>(&rank[base]);
        csr[offs[d.x] + r.x] = s.x;
        csr[offs[d.y] + r.y] = s.y;
        csr[offs[d.z] + r.z] = s.z;
        csr[offs[d.w] + r.w] = s.w;
    } else {
        for (int e = base; e < E; ++e) csr[offs[edst[e]] + rank[e]] = esrc[e];
    }
}

// ---------------- L1 GEMM (VALU, K=21) -> h fp8; scores via x @ cw ----------------
__global__ void k_gemm1(const float* __restrict__ x, const float* __restrict__ w,
                        const float* __restrict__ cw,
                        unsigned char* __restrict__ h8, float* __restrict__ asb,
                        float* __restrict__ adb, int N) {
    int tid = threadIdx.x;
    int row0 = blockIdx.x * 8;
    __shared__ float xs[8][21];
    int nrows = min(8, N - row0);
    for (int i = tid; i < nrows * 21; i += 256) xs[i / 21][i % 21] = x[row0 * 21 + i];
    __syncthreads();
    float wreg[21];
#pragma unroll
    for (int k = 0; k < 21; ++k) wreg[k] = w[k * 256 + tid];
    for (int r = 0; r < nrows; ++r) {
        float acc = 0.f;
#pragma unroll
        for (int k = 0; k < 21; ++k) acc = fmaf(xs[r][k], wreg[k], acc);
        h8[(size_t)(row0 + r) * 256 + tid] = f2f8(acc);
    }
    if (tid < 64) {
        int r = tid >> 3, j = tid & 7;
        if (r < nrows) {
            float s = 0.f;
#pragma unroll
            for (int k = 0; k < 21; ++k) s = fmaf(xs[r][k], cw[k * 8 + j], s);
            int row = row0 + r;
            if (j & 1) adb[row * 4 + (j >> 1)] = s;
            else       asb[row * 4 + (j >> 1)] = s;
        }
    }
}

// ---------------- L2 GEMM via MFMA (col-split waves) ----------------
__global__ __launch_bounds__(256) void k_gemm2_mfma(
        const unsigned short* __restrict__ in, const unsigned short* __restrict__ w2p,
        const float* __restrict__ as2f, const float* __restrict__ ad2f,
        unsigned char* __restrict__ h8, float* __restrict__ asb,
        float* __restrict__ adb, int N) {
    int tid = threadIdx.x;
    int wave = tid >> 6, lane = tid & 63;
    int g = lane >> 4, q = lane & 15;
    int row0 = blockIdx.x * 64;

    f32x4 acc[4][4];   // [row-group][cc]
#pragma unroll
    for (int rg = 0; rg < 4; ++rg)
#pragma unroll
        for (int cc = 0; cc < 4; ++cc) acc[rg][cc] = (f32x4)0.f;

    const unsigned short* aptr = in + (size_t)(row0 + q) * 256 + g * 8;
    const unsigned short* bptr = w2p + ((size_t)g * 256 + q) * 8 + wave * 512;

#pragma unroll
    for (int kt = 0; kt < 8; ++kt) {
        bf16x8 a[4];
#pragma unroll
        for (int rg = 0; rg < 4; ++rg)
            a[rg] = *reinterpret_cast<const bf16x8*>(aptr + (size_t)rg * 16 * 256 + kt * 32);
#pragma unroll
        for (int cc = 0; cc < 4; ++cc) {
            bf16x8 b = *reinterpret_cast<const bf16x8*>(bptr + (size_t)kt * 8192 + cc * 128);
#pragma unroll
            for (int rg = 0; rg < 4; ++rg)
                acc[rg][cc] = __builtin_amdgcn_mfma_f32_16x16x32_bf16(a[rg], b, acc[rg][cc], 0, 0, 0);
        }
    }

#pragma unroll
    for (int rg = 0; rg < 4; ++rg) {
#pragma unroll
        for (int cc = 0; cc < 4; ++cc) {
            int col = (wave * 4 + cc) * 16 + q;
#pragma unroll
            for (int r = 0; r < 4; ++r) {
                int row = row0 + rg * 16 + 4 * g + r;
                if (row < N) h8[(size_t)row * 256 + col] = f2f8(acc[rg][cc][r]);
            }
        }
    }

#pragma unroll
    for (int rg = 0; rg < 4; ++rg) {
        float s1[4] = {0.f, 0.f, 0.f, 0.f}, s2[4] = {0.f, 0.f, 0.f, 0.f};
#pragma unroll
        for (int cc = 0; cc < 4; ++cc) {
            int col = (wave * 4 + cc) * 16 + q;
            float ws_ = as2f[col], wd_ = ad2f[col];
#pragma unroll
            for (int r = 0; r < 4; ++r) {
                s1[r] = fmaf(acc[rg][cc][r], ws_, s1[r]);
                s2[r] = fmaf(acc[rg][cc][r], wd_, s2[r]);
            }
        }
#pragma unroll
        for (int m = 1; m < 16; m <<= 1) {
#pragma unroll
            for (int r = 0; r < 4; ++r) {
                s1[r] += __shfl_xor(s1[r], m);
                s2[r] += __shfl_xor(s2[r], m);
            }
        }
        if (q == 0) {
#pragma unroll
            for (int r = 0; r < 4; ++r) {
                int row = row0 + rg * 16 + 4 * g + r;
                if (row < N) { asb[row * 4 + wave] = s1[r]; adb[row * 4 + wave] = s2[r]; }
            }
        }
    }
}

// ---------------- L3 GEMM via MFMA -> h3 bf16 + scores ----------------
__global__ __launch_bounds__(256) void k_gemm3_mfma(
        const unsigned short* __restrict__ in, const unsigned short* __restrict__ w3p,
        const float* __restrict__ as3f, const float* __restrict__ ad3f,
        unsigned short* __restrict__ h3b, float* __restrict__ asb, float* __restrict__ adb,
        int N) {
    int tid = threadIdx.x;
    int wave = tid >> 6, lane = tid & 63;
    int g = lane >> 4, q = lane & 15;
    int row0 = blockIdx.x * 64 + wave * 16;

    f32x4 acc[2];
    acc[0] = (f32x4)0.f; acc[1] = (f32x4)0.f;

    const unsigned short* aptr = in + (size_t)(row0 + q) * 256 + g * 8;
    const unsigned short* bptr = w3p + ((size_t)g * 32 + q) * 8;

#pragma unroll
    for (int kt = 0; kt < 8; ++kt) {
        bf16x8 a = *reinterpret_cast<const bf16x8*>(aptr + kt * 32);
#pragma unroll
        for (int ct = 0; ct < 2; ++ct) {
            bf16x8 b = *reinterpret_cast<const bf16x8*>(bptr + (size_t)kt * 1024 + ct * 128);
            acc[ct] = __builtin_amdgcn_mfma_f32_16x16x32_bf16(a, b, acc[ct], 0, 0, 0);
        }
    }

    float s1[4] = {0.f, 0.f, 0.f, 0.f}, s2[4] = {0.f, 0.f, 0.f, 0.f};
#pragma unroll
    for (int ct = 0; ct < 2; ++ct) {
        int col = ct * 16 + q;
        float ws_ = as3f[col], wd_ = ad3f[col];
#pragma unroll
        for (int r = 0; r < 4; ++r) {
            int row = row0 + 4 * g + r;
            if (row < N) h3b[(size_t)row * 32 + col] = f2bf(acc[ct][r]);
            s1[r] = fmaf(acc[ct][r], ws_, s1[r]);
            s2[r] = fmaf(acc[ct][r], wd_, s2[r]);
        }
    }
#pragma unroll
    for (int m = 1; m < 16; m <<= 1) {
#pragma unroll
        for (int r = 0; r < 4; ++r) {
            s1[r] += __shfl_xor(s1[r], m);
            s2[r] += __shfl_xor(s2[r], m);
        }
    }
    if (q == 0) {
#pragma unroll
        for (int r = 0; r < 4; ++r) {
            int row = row0 + 4 * g + r;
            if (row < N) { asb[row] = s1[r]; adb[row] = s2[r]; }
        }
    }
}

// ---------------- gather (attention aggregate), F=256 fp8 -> bf16, 4 heads ----------------
// (Round-13 form: per-edge den, node-id broadcast — the 78 µs configuration)
__global__ void k_gather256(const unsigned int* __restrict__ h8,
                            const float* __restrict__ asb, const float* __restrict__ adb,
                            const int* __restrict__ offs, const int* __restrict__ csr,
                            const float* __restrict__ bias, unsigned short* __restrict__ out,
                            int N) {
    int tid = threadIdx.x;
    int lane = tid & 63;
    int v = blockIdx.x * 4 + (tid >> 6);
    if (v >= N) return;
    int head = lane >> 4;
    int j16 = lane & 15;
    int gbase = lane & 48;          // head-group base lane
    float ad = adb[v * 4 + head];
    float w0 = __expf(lrelu(asb[v * 4 + head] + ad));
    float den = w0;
    float a0, a1, a2, a3;
    {
        unsigned int hv = h8[(size_t)v * 64 + lane];
        f32x2 lo = __builtin_amdgcn_cvt_pk_f32_fp8(hv, false);
        f32x2 hi = __builtin_amdgcn_cvt_pk_f32_fp8(hv, true);
        a0 = w0 * lo.x; a1 = w0 * lo.y; a2 = w0 * hi.x; a3 = w0 * hi.y;
    }
    int beg = offs[v], end = offs[v + 1];
    for (int c = beg; c < end; c += 16) {
        int idx = c + j16;
        int u = 0;
        float w = 0.f;
        if (idx < end) {
            u = csr[idx];
            w = __expf(lrelu(asb[u * 4 + head] + ad));
        }
#pragma unroll
        for (int j = 0; j < 16; ++j) {
            float wj = __shfl(w, gbase | j);
            int   uj = __shfl(u, gbase | j);
            den += wj;
            unsigned int hv = h8[(size_t)uj * 64 + lane];
            f32x2 lo = __builtin_amdgcn_cvt_pk_f32_fp8(hv, false);
            f32x2 hi = __builtin_amdgcn_cvt_pk_f32_fp8(hv, true);
            a0 = fmaf(wj, lo.x, a0); a1 = fmaf(wj, lo.y, a1);
            a2 = fmaf(wj, hi.x, a2); a3 = fmaf(wj, hi.y, a3);
        }
    }
    float inv = 1.f / (den + 1e-16f);
    int f0 = 4 * lane;
    unsigned int w01 = (unsigned int)f2bf(eluf(a0 * inv + bias[f0 + 0]))
                     | ((unsigned int)f2bf(eluf(a1 * inv + bias[f0 + 1])) << 16);
    unsigned int w23 = (unsigned int)f2bf(eluf(a2 * inv + bias[f0 + 2]))
                     | ((unsigned int)f2bf(eluf(a3 * inv + bias[f0 + 3])) << 16);
    u32x2 o; o.x = w01; o.y = w23;
    __builtin_nontemporal_store(o, reinterpret_cast<u32x2*>(&out[(size_t)v * 256 + f0]));
}

// ---------------- gather, F=32 bf16 -> fp32 out, 1 head — chunked ILP (Round-13 form) ----------------
__global__ void k_gather32(const unsigned short* __restrict__ h, const float* __restrict__ asb,
                           const float* __restrict__ adb, const int* __restrict__ offs,
                           const int* __restrict__ csr, const float* __restrict__ bias,
                           float* __restrict__ out, int N) {
    int tid = threadIdx.x;
    int v = blockIdx.x * 8 + (tid >> 5);
    int c = tid & 31;
    int gbase = tid & 32;           // 32-lane group base within the wave
    if (v >= N) return;
    float ad = adb[v];
    float w0 = __expf(lrelu(asb[v] + ad));
    float den = w0;
    float acc = w0 * bf2f(h[(size_t)v * 32 + c]);
    int beg = offs[v], end = offs[v + 1];
    for (int e0 = beg; e0 < end; e0 += 32) {
        int idx = e0 + c;
        int u = 0;
        float w = 0.f;
        if (idx < end) {
            u = csr[idx];
            w = __expf(lrelu(asb[u] + ad));
        }
#pragma unroll
        for (int j = 0; j < 32; ++j) {
            float wj = __shfl(w, gbase | j);
            int   uj = __shfl(u, gbase | j);
            den += wj;
            acc = fmaf(wj, bf2f(h[(size_t)uj * 32 + c]), acc);
        }
    }
    float o = eluf(acc / (den + 1e-16f) + bias[c]);
    __builtin_nontemporal_store(o, &out[(size_t)v * 32 + c]);
}

// ---------------- fused mean-pool + MLP head ----------------
__global__ __launch_bounds__(256) void k_pool_head(
        const float* __restrict__ h, const int* __restrict__ batch, int N,
        const float* __restrict__ fw1, const float* __restrict__ fb1,
        const float* __restrict__ fw2, const float* __restrict__ fb2,
        const float* __restrict__ fw3, const float* __restrict__ fb3,
        float* __restrict__ out, int G) {
    int g = blockIdx.x;
    int tid = threadIdx.x;
    __shared__ int bounds[2];
    __shared__ float red[8][32];
    __shared__ float pooled[32];
    __shared__ float t1[64];
    __shared__ float t2[32];

    if (tid < 2) {
        int target = g + tid;
        int lo = 0, hi = N;
        while (lo < hi) {
            int mid = (lo + hi) >> 1;
            if (batch[mid] < target) lo = mid + 1; else hi = mid;
        }
        bounds[tid] = lo;
    }
    __syncthreads();
    int beg = bounds[0], end = bounds[1];

    int f = tid & 31, r = tid >> 5;
    float s = 0.f;
    for (int i = beg + r; i < end; i += 8) s += h[(size_t)i * 32 + f];
    red[r][f] = s;
    __syncthreads();

    if (tid < 32) {
        float t = 0.f;
#pragma unroll
        for (int k = 0; k < 8; ++k) t += red[k][tid];
        float invc = 1.f / fmaxf((float)(end - beg), 1.f);
        pooled[tid] = t * invc;
    }
    __syncthreads();

    if (tid < 64) {
        float a = fb1[tid];
#pragma unroll
        for (int k = 0; k < 32; ++k) a = fmaf(pooled[k], fw1[k * 64 + tid], a);
        t1[tid] = fmaxf(a, 0.f);
    }
    __syncthreads();
    if (tid < 32) {
        float a = fb2[tid];
#pragma unroll
        for (int k = 0; k < 64; ++k) a = fmaf(t1[k], fw2[k * 32 + tid], a);
        t2[tid] = fmaxf(a, 0.f);
    }
    __syncthreads();
    if (tid == 0) {
        float o = fb3[0];
#pragma unroll
        for (int k = 0; k < 32; ++k) o = fmaf(t2[k], fw3[k], o);
        out[g] = 1.f / (1.f + __expf(-o));
    }
}

// ---------------- host ----------------
extern "C" void kernel_launch(void* const* d_in, const int* in_sizes, int n_in,
                              void* d_out, int out_size, void* d_ws, size_t ws_size,
                              hipStream_t stream) {
    const float* x    = (const float*)d_in[0];
    const int*   ei   = (const int*)d_in[1];
    const int*   batch= (const int*)d_in[2];
    const float* w1   = (const float*)d_in[3];
    const float* as1  = (const float*)d_in[4];
    const float* ad1  = (const float*)d_in[5];
    const float* b1   = (const float*)d_in[6];
    const float* w2   = (const float*)d_in[7];
    const float* as2  = (const float*)d_in[8];
    const float* ad2  = (const float*)d_in[9];
    const float* b2   = (const float*)d_in[10];
    const float* w3   = (const float*)d_in[11];
    const float* as3  = (const float*)d_in[12];
    const float* ad3  = (const float*)d_in[13];
    const float* b3   = (const float*)d_in[14];
    const float* fw1  = (const float*)d_in[15];
    const float* fb1  = (const float*)d_in[16];
    const float* fw2  = (const float*)d_in[17];
    const float* fb2  = (const float*)d_in[18];
    const float* fw3  = (const float*)d_in[19];
    const float* fb3  = (const float*)d_in[20];
    float* outp = (float*)d_out;

    const int N = in_sizes[0] / 21;
    const int E = in_sizes[1] / 2;
    const int G = out_size;

    // ---- workspace carve ----
    char* p = (char*)d_ws;
    auto alloc = [&](size_t bytes) -> void* {
        void* r = (void*)p;
        p += (bytes + 255) & ~(size_t)255;
        return r;
    };
    int*   deg  = (int*)alloc((size_t)N * 4);
    int*   offs = (int*)alloc((size_t)(N + 1) * 4);
    int*   csr  = (int*)alloc((size_t)E * 4);
    unsigned short* rank = (unsigned short*)alloc((size_t)E * 2);
    int*   bsum = (int*)alloc((size_t)256 * 4);
    unsigned char*  h8  = (unsigned char*)alloc((size_t)N * 256);       // fp8 gather operand
    unsigned short* hbf = (unsigned short*)alloc((size_t)N * 256 * 2);  // bf16 gather output
    unsigned short* h3b = (unsigned short*)alloc((size_t)N * 32 * 2);   // bf16 layer-3 operand
    float* hP   = (float*)alloc((size_t)N * 32 * 4);
    float* asb  = (float*)alloc((size_t)N * 4 * 4);
    float* adb  = (float*)alloc((size_t)N * 4 * 4);
    unsigned short* w2p = (unsigned short*)alloc((size_t)256 * 256 * 2);
    unsigned short* w3p = (unsigned short*)alloc((size_t)256 * 32 * 2);
    float* cw   = (float*)alloc((size_t)21 * 8 * 4);                    // L1 combined score weights

    const int* esrc = ei;
    const int* edst = ei + E;

    (void)hipMemsetAsync(deg, 0, (size_t)N * 4, stream);

    const int sb = (N + 1023) / 1024;          // scan blocks (<= 256)
    const int DB = (E + 1023) / 1024;          // deg blocks (4 edges/thread)
    const int SB = (E + 1023) / 1024;          // scatter blocks (4 edges/thread)

    // ---- CSR build: deg+rank+packs+cw, scan, atomic-free scatter ----
    k_deg_pack<<<DB + 256 + 32 + 1, 256, 0, stream>>>(edst, deg, rank, E, DB,
                                                      w2, w2p, w3, w3p, w1, as1, ad1, cw);
    k_scan1<<<sb, 1024, 0, stream>>>(deg, bsum, N);
    k_scan2<<<1, 256, 0, stream>>>(bsum, sb);
    k_scan3<<<sb, 1024, 0, stream>>>(deg, bsum, offs, N);
    k_scatter<<<SB, 256, 0, stream>>>(esrc, edst, rank, offs, csr, E);

    const int gblk = (N + 63) / 64;

    // ---- layer 1 ----
    k_gemm1<<<(N + 7) / 8, 256, 0, stream>>>(x, w1, cw, h8, asb, adb, N);
    k_gather256<<<(N + 3) / 4, 256, 0, stream>>>((const unsigned int*)h8, asb, adb, offs, csr, b1, hbf, N);

    // ---- layer 2 ----
    k_gemm2_mfma<<<gblk, 256, 0, stream>>>(hbf, w2p, as2, ad2, h8, asb, adb, N);
    k_gather256<<<(N + 3) / 4, 256, 0, stream>>>((const unsigned int*)h8, asb, adb, offs, csr, b2, hbf, N);

    // ---- layer 3 ----
    k_gemm3_mfma<<<gblk, 256, 0, stream>>>(hbf, w3p, as3, ad3, h3b, asb, adb, N);
    k_gather32<<<(N + 7) / 8, 256, 0, stream>>>(h3b, asb, adb, offs, csr, b3, hP, N);

    // ---- fused pool + head ----
    k_pool_head<<<G, 256, 0, stream>>>(hP, batch, N, fw1, fb1, fw2, fb2, fw3, fb3, outp, G);
}

// Round 16
// 421.847 us; speedup vs baseline: 1.0663x; 1.0391x over previous
//
#include <hip/hip_runtime.h>
#include <math.h>

typedef float f4 __attribute__((ext_vector_type(4)));
typedef float f32x4 __attribute__((ext_vector_type(4)));
typedef float f32x2 __attribute__((ext_vector_type(2)));
typedef short bf16x8 __attribute__((ext_vector_type(8)));
typedef unsigned int u32x2 __attribute__((ext_vector_type(2)));
typedef int i32x4 __attribute__((ext_vector_type(4)));
typedef unsigned short u16x4 __attribute__((ext_vector_type(4)));

// ---------------- device helpers ----------------
__device__ __forceinline__ float lrelu(float x) { return x >= 0.f ? x : 0.2f * x; }
__device__ __forceinline__ float eluf(float x)  { return x > 0.f ? x : __expf(x) - 1.f; }

__device__ __forceinline__ float bf2f(unsigned short u) {
    union { unsigned int i; float f; } c; c.i = ((unsigned int)u) << 16; return c.f;
}
__device__ __forceinline__ unsigned short f2bf(float f) {
    union { float f; unsigned int i; } c; c.f = f;
    unsigned int r = c.i + 0x7fffu + ((c.i >> 16) & 1u);   // RNE
    return (unsigned short)(r >> 16);
}
__device__ __forceinline__ unsigned char f2f8(float f) {
    return (unsigned char)(__builtin_amdgcn_cvt_pk_fp8_f32(f, f, 0u, false) & 0xffu);
}

// ---------------- fused: deg+rank, fp8 weight packs, L1 combined score weights ----------------
__global__ void k_deg_pack(const int* __restrict__ edst, int* __restrict__ deg,
                           unsigned short* __restrict__ rank, int E, int DB,
                           const float* __restrict__ w2, unsigned char* __restrict__ w2p8,
                           const float* __restrict__ w3, unsigned char* __restrict__ w3p8,
                           const float* __restrict__ w1, const float* __restrict__ as1,
                           const float* __restrict__ ad1, float* __restrict__ cw) {
    int b = blockIdx.x;
    int tid = threadIdx.x;
    if (b < DB) {
        int base = (b * 256 + tid) * 4;
        if (base + 3 < E) {
            i32x4 d = *reinterpret_cast<const i32x4*>(&edst[base]);
            u16x4 r;
            r.x = (unsigned short)atomicAdd(&deg[d.x], 1);
            r.y = (unsigned short)atomicAdd(&deg[d.y], 1);
            r.z = (unsigned short)atomicAdd(&deg[d.z], 1);
            r.w = (unsigned short)atomicAdd(&deg[d.w], 1);
            *reinterpret_cast<u16x4*>(&rank[base]) = r;
        } else {
            for (int e = base; e < E; ++e)
                rank[e] = (unsigned short)atomicAdd(&deg[edst[e]], 1);
        }
    } else if (b < DB + 256) {
        int i = (b - DB) * 256 + tid;          // w2: 256x256
        int k = i >> 8, c = i & 255;
        w2p8[((size_t)(k >> 3) * 256 + c) * 8 + (k & 7)] = f2f8(w2[i]);
    } else if (b < DB + 256 + 32) {
        int i = (b - DB - 256) * 256 + tid;    // w3: 256x32
        int k = i >> 5, c = i & 31;
        w3p8[((size_t)(k >> 3) * 32 + c) * 8 + (k & 7)] = f2f8(w3[i]);
    } else {
        if (tid < 168) {                       // cw: 21x8 combined score weights
            int k = tid >> 3, j = tid & 7;
            int h = j >> 1;
            const float* av = (j & 1) ? ad1 : as1;
            float s = 0.f;
            for (int c = 0; c < 64; ++c)
                s = fmaf(w1[k * 256 + h * 64 + c], av[h * 64 + c], s);
            cw[k * 8 + j] = s;
        }
    }
}

// ---- multi-block exclusive scan over deg[N] -> offs[N+1] ----
__global__ __launch_bounds__(1024) void k_scan1(const int* __restrict__ deg,
                                                int* __restrict__ bsum, int N) {
    int t = threadIdx.x;
    int i = blockIdx.x * 1024 + t;
    int v = (i < N) ? deg[i] : 0;
#pragma unroll
    for (int m = 32; m; m >>= 1) v += __shfl_xor(v, m);
    __shared__ int ws[16];
    if ((t & 63) == 0) ws[t >> 6] = v;
    __syncthreads();
    if (t < 16) {
        int s = ws[t];
#pragma unroll
        for (int m = 8; m; m >>= 1) s += __shfl_xor(s, m);
        if (t == 0) bsum[blockIdx.x] = s;
    }
}

__global__ void k_scan2(int* __restrict__ bsum, int B) {
    __shared__ int sm[256];
    int t = threadIdx.x;
    int v = (t < B) ? bsum[t] : 0;
    sm[t] = v;
    __syncthreads();
    for (int d = 1; d < 256; d <<= 1) {
        int x = (t >= d) ? sm[t - d] : 0;
        __syncthreads();
        sm[t] += x;
        __syncthreads();
    }
    if (t < B) bsum[t] = sm[t] - v;
}

__global__ __launch_bounds__(1024) void k_scan3(const int* __restrict__ deg,
                                                const int* __restrict__ bsum,
                                                int* __restrict__ offs, int N) {
    __shared__ int sm[1024];
    int t = threadIdx.x;
    int i = blockIdx.x * 1024 + t;
    int v = (i < N) ? deg[i] : 0;
    sm[t] = v;
    __syncthreads();
    for (int d = 1; d < 1024; d <<= 1) {
        int x = (t >= d) ? sm[t - d] : 0;
        __syncthreads();
        sm[t] += x;
        __syncthreads();
    }
    int pref = bsum[blockIdx.x] + sm[t] - v;
    if (i < N) offs[i] = pref;
    if (i == N - 1) offs[N] = pref + v;
}

// ---------------- atomic-free scatter: csr[offs[dst]+rank] = src ----------------
__global__ void k_scatter(const int* __restrict__ esrc, const int* __restrict__ edst,
                          const unsigned short* __restrict__ rank,
                          const int* __restrict__ offs, int* __restrict__ csr, int E) {
    int base = (blockIdx.x * 256 + threadIdx.x) * 4;
    if (base + 3 < E) {
        i32x4 s = *reinterpret_cast<const i32x4*>(&esrc[base]);
        i32x4 d = *reinterpret_cast<const i32x4*>(&edst[base]);
        u16x4 r = *reinterpret_cast<const u16x4*>(&rank[base]);
        csr[offs[d.x] + r.x] = s.x;
        csr[offs[d.y] + r.y] = s.y;
        csr[offs[d.z] + r.z] = s.z;
        csr[offs[d.w] + r.w] = s.w;
    } else {
        for (int e = base; e < E; ++e) csr[offs[edst[e]] + rank[e]] = esrc[e];
    }
}

// ---------------- L1 GEMM (VALU, K=21) -> h fp8; scores via x @ cw ----------------
__global__ void k_gemm1(const float* __restrict__ x, const float* __restrict__ w,
                        const float* __restrict__ cw,
                        unsigned char* __restrict__ h8, float* __restrict__ asb,
                        float* __restrict__ adb, int N) {
    int tid = threadIdx.x;
    int row0 = blockIdx.x * 8;
    __shared__ float xs[8][21];
    int nrows = min(8, N - row0);
    for (int i = tid; i < nrows * 21; i += 256) xs[i / 21][i % 21] = x[row0 * 21 + i];
    __syncthreads();
    float wreg[21];
#pragma unroll
    for (int k = 0; k < 21; ++k) wreg[k] = w[k * 256 + tid];
    for (int r = 0; r < nrows; ++r) {
        float acc = 0.f;
#pragma unroll
        for (int k = 0; k < 21; ++k) acc = fmaf(xs[r][k], wreg[k], acc);
        h8[(size_t)(row0 + r) * 256 + tid] = f2f8(acc);
    }
    if (tid < 64) {
        int r = tid >> 3, j = tid & 7;
        if (r < nrows) {
            float s = 0.f;
#pragma unroll
            for (int k = 0; k < 21; ++k) s = fmaf(xs[r][k], cw[k * 8 + j], s);
            int row = row0 + r;
            if (j & 1) adb[row * 4 + (j >> 1)] = s;
            else       asb[row * 4 + (j >> 1)] = s;
        }
    }
}

// ---------------- L2 GEMM via fp8 MFMA (col-split waves): in fp8 @ w2 fp8 ----------------
__global__ __launch_bounds__(256) void k_gemm2_mfma(
        const unsigned char* __restrict__ in8, const unsigned char* __restrict__ w2p8,
        const float* __restrict__ as2f, const float* __restrict__ ad2f,
        unsigned char* __restrict__ h8, float* __restrict__ asb,
        float* __restrict__ adb, int N) {
    int tid = threadIdx.x;
    int wave = tid >> 6, lane = tid & 63;
    int g = lane >> 4, q = lane & 15;
    int row0 = blockIdx.x * 64;

    f32x4 acc[4][4];   // [row-group][cc]
#pragma unroll
    for (int rg = 0; rg < 4; ++rg)
#pragma unroll
        for (int cc = 0; cc < 4; ++cc) acc[rg][cc] = (f32x4)0.f;

    const unsigned char* aptr = in8 + (size_t)(row0 + q) * 256 + g * 8;
    const unsigned char* bptr = w2p8 + (size_t)g * 2048 + q * 8 + wave * 512;

#pragma unroll
    for (int kt = 0; kt < 8; ++kt) {
        long a[4];
#pragma unroll
        for (int rg = 0; rg < 4; ++rg)
            a[rg] = *reinterpret_cast<const long*>(aptr + (size_t)rg * 16 * 256 + kt * 32);
#pragma unroll
        for (int cc = 0; cc < 4; ++cc) {
            long b = *reinterpret_cast<const long*>(bptr + (size_t)kt * 8192 + cc * 128);
#pragma unroll
            for (int rg = 0; rg < 4; ++rg)
                acc[rg][cc] = __builtin_amdgcn_mfma_f32_16x16x32_fp8_fp8(a[rg], b, acc[rg][cc], 0, 0, 0);
        }
    }

#pragma unroll
    for (int rg = 0; rg < 4; ++rg) {
#pragma unroll
        for (int cc = 0; cc < 4; ++cc) {
            int col = (wave * 4 + cc) * 16 + q;
#pragma unroll
            for (int r = 0; r < 4; ++r) {
                int row = row0 + rg * 16 + 4 * g + r;
                if (row < N) h8[(size_t)row * 256 + col] = f2f8(acc[rg][cc][r]);
            }
        }
    }

#pragma unroll
    for (int rg = 0; rg < 4; ++rg) {
        float s1[4] = {0.f, 0.f, 0.f, 0.f}, s2[4] = {0.f, 0.f, 0.f, 0.f};
#pragma unroll
        for (int cc = 0; cc < 4; ++cc) {
            int col = (wave * 4 + cc) * 16 + q;
            float ws_ = as2f[col], wd_ = ad2f[col];
#pragma unroll
            for (int r = 0; r < 4; ++r) {
                s1[r] = fmaf(acc[rg][cc][r], ws_, s1[r]);
                s2[r] = fmaf(acc[rg][cc][r], wd_, s2[r]);
            }
        }
#pragma unroll
        for (int m = 1; m < 16; m <<= 1) {
#pragma unroll
            for (int r = 0; r < 4; ++r) {
                s1[r] += __shfl_xor(s1[r], m);
                s2[r] += __shfl_xor(s2[r], m);
            }
        }
        if (q == 0) {
#pragma unroll
            for (int r = 0; r < 4; ++r) {
                int row = row0 + rg * 16 + 4 * g + r;
                if (row < N) { asb[row * 4 + wave] = s1[r]; adb[row * 4 + wave] = s2[r]; }
            }
        }
    }
}

// ---------------- L3 GEMM via fp8 MFMA -> h3 bf16 + scores ----------------
__global__ __launch_bounds__(256) void k_gemm3_mfma(
        const unsigned char* __restrict__ in8, const unsigned char* __restrict__ w3p8,
        const float* __restrict__ as3f, const float* __restrict__ ad3f,
        unsigned short* __restrict__ h3b, float* __restrict__ asb, float* __restrict__ adb,
        int N) {
    int tid = threadIdx.x;
    int wave = tid >> 6, lane = tid & 63;
    int g = lane >> 4, q = lane & 15;
    int row0 = blockIdx.x * 64 + wave * 16;

    f32x4 acc[2];
    acc[0] = (f32x4)0.f; acc[1] = (f32x4)0.f;

    const unsigned char* aptr = in8 + (size_t)(row0 + q) * 256 + g * 8;
    const unsigned char* bptr = w3p8 + (size_t)g * 256 + q * 8;

#pragma unroll
    for (int kt = 0; kt < 8; ++kt) {
        long a = *reinterpret_cast<const long*>(aptr + kt * 32);
#pragma unroll
        for (int ct = 0; ct < 2; ++ct) {
            long b = *reinterpret_cast<const long*>(bptr + (size_t)kt * 1024 + ct * 128);
            acc[ct] = __builtin_amdgcn_mfma_f32_16x16x32_fp8_fp8(a, b, acc[ct], 0, 0, 0);
        }
    }

    float s1[4] = {0.f, 0.f, 0.f, 0.f}, s2[4] = {0.f, 0.f, 0.f, 0.f};
#pragma unroll
    for (int ct = 0; ct < 2; ++ct) {
        int col = ct * 16 + q;
        float ws_ = as3f[col], wd_ = ad3f[col];
#pragma unroll
        for (int r = 0; r < 4; ++r) {
            int row = row0 + 4 * g + r;
            if (row < N) h3b[(size_t)row * 32 + col] = f2bf(acc[ct][r]);
            s1[r] = fmaf(acc[ct][r], ws_, s1[r]);
            s2[r] = fmaf(acc[ct][r], wd_, s2[r]);
        }
    }
#pragma unroll
    for (int m = 1; m < 16; m <<= 1) {
#pragma unroll
        for (int r = 0; r < 4; ++r) {
            s1[r] += __shfl_xor(s1[r], m);
            s2[r] += __shfl_xor(s2[r], m);
        }
    }
    if (q == 0) {
#pragma unroll
        for (int r = 0; r < 4; ++r) {
            int row = row0 + 4 * g + r;
            if (row < N) { asb[row] = s1[r]; adb[row] = s2[r]; }
        }
    }
}

// ---------------- gather (attention aggregate), F=256 fp8 -> fp8 out, 4 heads ----------------
__global__ void k_gather256(const unsigned int* __restrict__ h8,
                            const float* __restrict__ asb, const float* __restrict__ adb,
                            const int* __restrict__ offs, const int* __restrict__ csr,
                            const float* __restrict__ bias, unsigned int* __restrict__ out8,
                            int N) {
    int tid = threadIdx.x;
    int lane = tid & 63;
    int v = blockIdx.x * 4 + (tid >> 6);
    if (v >= N) return;
    int head = lane >> 4;
    int j16 = lane & 15;
    int gbase = lane & 48;          // head-group base lane
    float ad = adb[v * 4 + head];
    float w0 = __expf(lrelu(asb[v * 4 + head] + ad));
    float den = w0;
    float a0, a1, a2, a3;
    {
        unsigned int hv = h8[(size_t)v * 64 + lane];
        f32x2 lo = __builtin_amdgcn_cvt_pk_f32_fp8(hv, false);
        f32x2 hi = __builtin_amdgcn_cvt_pk_f32_fp8(hv, true);
        a0 = w0 * lo.x; a1 = w0 * lo.y; a2 = w0 * hi.x; a3 = w0 * hi.y;
    }
    int beg = offs[v], end = offs[v + 1];
    for (int c = beg; c < end; c += 16) {
        int idx = c + j16;
        int u = 0;
        float w = 0.f;
        if (idx < end) {
            u = csr[idx];
            w = __expf(lrelu(asb[u * 4 + head] + ad));
        }
#pragma unroll
        for (int j = 0; j < 16; ++j) {
            float wj = __shfl(w, gbase | j);
            int   uj = __shfl(u, gbase | j);
            den += wj;
            unsigned int hv = h8[(size_t)uj * 64 + lane];
            f32x2 lo = __builtin_amdgcn_cvt_pk_f32_fp8(hv, false);
            f32x2 hi = __builtin_amdgcn_cvt_pk_f32_fp8(hv, true);
            a0 = fmaf(wj, lo.x, a0); a1 = fmaf(wj, lo.y, a1);
            a2 = fmaf(wj, hi.x, a2); a3 = fmaf(wj, hi.y, a3);
        }
    }
    float inv = 1.f / (den + 1e-16f);
    int f0 = 4 * lane;
    float o0 = eluf(a0 * inv + bias[f0 + 0]);
    float o1 = eluf(a1 * inv + bias[f0 + 1]);
    float o2 = eluf(a2 * inv + bias[f0 + 2]);
    float o3 = eluf(a3 * inv + bias[f0 + 3]);
    unsigned int wpk = __builtin_amdgcn_cvt_pk_fp8_f32(o0, o1, 0u, false);
    wpk = __builtin_amdgcn_cvt_pk_fp8_f32(o2, o3, wpk, true);
    __builtin_nontemporal_store(wpk, &out8[(size_t)v * 64 + lane]);
}

// ---------------- gather, F=32 bf16 -> fp32 out, 1 head — chunked ILP ----------------
__global__ void k_gather32(const unsigned short* __restrict__ h, const float* __restrict__ asb,
                           const float* __restrict__ adb, const int* __restrict__ offs,
                           const int* __restrict__ csr, const float* __restrict__ bias,
                           float* __restrict__ out, int N) {
    int tid = threadIdx.x;
    int v = blockIdx.x * 8 + (tid >> 5);
    int c = tid & 31;
    int gbase = tid & 32;           // 32-lane group base within the wave
    if (v >= N) return;
    float ad = adb[v];
    float w0 = __expf(lrelu(asb[v] + ad));
    float den = w0;
    float acc = w0 * bf2f(h[(size_t)v * 32 + c]);
    int beg = offs[v], end = offs[v + 1];
    for (int e0 = beg; e0 < end; e0 += 32) {
        int idx = e0 + c;
        int u = 0;
        float w = 0.f;
        if (idx < end) {
            u = csr[idx];
            w = __expf(lrelu(asb[u] + ad));
        }
#pragma unroll
        for (int j = 0; j < 32; ++j) {
            float wj = __shfl(w, gbase | j);
            int   uj = __shfl(u, gbase | j);
            den += wj;
            acc = fmaf(wj, bf2f(h[(size_t)uj * 32 + c]), acc);
        }
    }
    float o = eluf(acc / (den + 1e-16f) + bias[c]);
    __builtin_nontemporal_store(o, &out[(size_t)v * 32 + c]);
}

// ---------------- fused mean-pool + MLP head ----------------
__global__ __launch_bounds__(256) void k_pool_head(
        const float* __restrict__ h, const int* __restrict__ batch, int N,
        const float* __restrict__ fw1, const float* __restrict__ fb1,
        const float* __restrict__ fw2, const float* __restrict__ fb2,
        const float* __restrict__ fw3, const float* __restrict__ fb3,
        float* __restrict__ out, int G) {
    int g = blockIdx.x;
    int tid = threadIdx.x;
    __shared__ int bounds[2];
    __shared__ float red[8][32];
    __shared__ float pooled[32];
    __shared__ float t1[64];
    __shared__ float t2[32];

    if (tid < 2) {
        int target = g + tid;
        int lo = 0, hi = N;
        while (lo < hi) {
            int mid = (lo + hi) >> 1;
            if (batch[mid] < target) lo = mid + 1; else hi = mid;
        }
        bounds[tid] = lo;
    }
    __syncthreads();
    int beg = bounds[0], end = bounds[1];

    int f = tid & 31, r = tid >> 5;
    float s = 0.f;
    for (int i = beg + r; i < end; i += 8) s += h[(size_t)i * 32 + f];
    red[r][f] = s;
    __syncthreads();

    if (tid < 32) {
        float t = 0.f;
#pragma unroll
        for (int k = 0; k < 8; ++k) t += red[k][tid];
        float invc = 1.f / fmaxf((float)(end - beg), 1.f);
        pooled[tid] = t * invc;
    }
    __syncthreads();

    if (tid < 64) {
        float a = fb1[tid];
#pragma unroll
        for (int k = 0; k < 32; ++k) a = fmaf(pooled[k], fw1[k * 64 + tid], a);
        t1[tid] = fmaxf(a, 0.f);
    }
    __syncthreads();
    if (tid < 32) {
        float a = fb2[tid];
#pragma unroll
        for (int k = 0; k < 64; ++k) a = fmaf(t1[k], fw2[k * 32 + tid], a);
        t2[tid] = fmaxf(a, 0.f);
    }
    __syncthreads();
    if (tid == 0) {
        float o = fb3[0];
#pragma unroll
        for (int k = 0; k < 32; ++k) o = fmaf(t2[k], fw3[k], o);
        out[g] = 1.f / (1.f + __expf(-o));
    }
}

// ---------------- host ----------------
extern "C" void kernel_launch(void* const* d_in, const int* in_sizes, int n_in,
                              void* d_out, int out_size, void* d_ws, size_t ws_size,
                              hipStream_t stream) {
    const float* x    = (const float*)d_in[0];
    const int*   ei   = (const int*)d_in[1];
    const int*   batch= (const int*)d_in[2];
    const float* w1   = (const float*)d_in[3];
    const float* as1  = (const float*)d_in[4];
    const float* ad1  = (const float*)d_in[5];
    const float* b1   = (const float*)d_in[6];
    const float* w2   = (const float*)d_in[7];
    const float* as2  = (const float*)d_in[8];
    const float* ad2  = (const float*)d_in[9];
    const float* b2   = (const float*)d_in[10];
    const float* w3   = (const float*)d_in[11];
    const float* as3  = (const float*)d_in[12];
    const float* ad3  = (const float*)d_in[13];
    const float* b3   = (const float*)d_in[14];
    const float* fw1  = (const float*)d_in[15];
    const float* fb1  = (const float*)d_in[16];
    const float* fw2  = (const float*)d_in[17];
    const float* fb2  = (const float*)d_in[18];
    const float* fw3  = (const float*)d_in[19];
    const float* fb3  = (const float*)d_in[20];
    float* outp = (float*)d_out;

    const int N = in_sizes[0] / 21;
    const int E = in_sizes[1] / 2;
    const int G = out_size;

    // ---- workspace carve ----
    char* p = (char*)d_ws;
    auto alloc = [&](size_t bytes) -> void* {
        void* r = (void*)p;
        p += (bytes + 255) & ~(size_t)255;
        return r;
    };
    int*   deg  = (int*)alloc((size_t)N * 4);
    int*   offs = (int*)alloc((size_t)(N + 1) * 4);
    int*   csr  = (int*)alloc((size_t)E * 4);
    unsigned short* rank = (unsigned short*)alloc((size_t)E * 2);
    int*   bsum = (int*)alloc((size_t)256 * 4);
    unsigned char* h8  = (unsigned char*)alloc((size_t)N * 256);   // fp8 gather operand
    unsigned char* hb8 = (unsigned char*)alloc((size_t)N * 256);   // fp8 gather output / GEMM input
    unsigned short* h3b = (unsigned short*)alloc((size_t)N * 32 * 2);
    float* hP   = (float*)alloc((size_t)N * 32 * 4);
    float* asb  = (float*)alloc((size_t)N * 4 * 4);
    float* adb  = (float*)alloc((size_t)N * 4 * 4);
    unsigned char* w2p8 = (unsigned char*)alloc((size_t)256 * 256);
    unsigned char* w3p8 = (unsigned char*)alloc((size_t)256 * 32);
    float* cw   = (float*)alloc((size_t)21 * 8 * 4);

    const int* esrc = ei;
    const int* edst = ei + E;

    (void)hipMemsetAsync(deg, 0, (size_t)N * 4, stream);

    const int sb = (N + 1023) / 1024;
    const int DB = (E + 1023) / 1024;
    const int SB = (E + 1023) / 1024;

    // ---- CSR build: deg+rank+packs+cw, scan, atomic-free scatter ----
    k_deg_pack<<<DB + 256 + 32 + 1, 256, 0, stream>>>(edst, deg, rank, E, DB,
                                                      w2, w2p8, w3, w3p8, w1, as1, ad1, cw);
    k_scan1<<<sb, 1024, 0, stream>>>(deg, bsum, N);
    k_scan2<<<1, 256, 0, stream>>>(bsum, sb);
    k_scan3<<<sb, 1024, 0, stream>>>(deg, bsum, offs, N);
    k_scatter<<<SB, 256, 0, stream>>>(esrc, edst, rank, offs, csr, E);

    const int gblk = (N + 63) / 64;

    // ---- layer 1 ----
    k_gemm1<<<(N + 7) / 8, 256, 0, stream>>>(x, w1, cw, h8, asb, adb, N);
    k_gather256<<<(N + 3) / 4, 256, 0, stream>>>((const unsigned int*)h8, asb, adb, offs, csr, b1,
                                                 (unsigned int*)hb8, N);

    // ---- layer 2 ----
    k_gemm2_mfma<<<gblk, 256, 0, stream>>>(hb8, w2p8, as2, ad2, h8, asb, adb, N);
    k_gather256<<<(N + 3) / 4, 256, 0, stream>>>((const unsigned int*)h8, asb, adb, offs, csr, b2,
                                                 (unsigned int*)hb8, N);

    // ---- layer 3 ----
    k_gemm3_mfma<<<gblk, 256, 0, stream>>>(hb8, w3p8, as3, ad3, h3b, asb, adb, N);
    k_gather32<<<(N + 7) / 8, 256, 0, stream>>>(h3b, asb, adb, offs, csr, b3, hP, N);

    // ---- fused pool + head ----
    k_pool_head<<<G, 256, 0, stream>>>(hP, batch, N, fw1, fb1, fw2, fb2, fw3, fb3, outp, G);
}